// Round 1
// baseline (1344.716 us; speedup 1.0000x reference)
//
#include <hip/hip_runtime.h>
#include <math.h>

#ifndef M_PI
#define M_PI 3.14159265358979323846
#endif

// ---------------- architecture constants ----------------
#define BLOCK 256
#define BPTS  64          // points per block
#define DIM   136         // hidden width = 8*(1+2*8)
#define WP    152         // weight LDS pitch (halves): 304B rows -> 16B aligned, 2-way-max bank conflict
#define TMASK 524287u     // T-1, T = 2^19
#define LVLSTRIDE 4194304 // T*F floats per level

typedef _Float16 half8v __attribute__((ext_vector_type(8)));
typedef _Float16 half4v __attribute__((ext_vector_type(4)));
typedef _Float16 half2v __attribute__((ext_vector_type(2)));

union H8 { half8v v; half2v p[4]; };

struct FfbConsts {
    float freqs[8];
    int   res[7];
};

// sin/cos via revolution-space reduction + HW v_sin/v_cos (valid domain [0,1) after fract).
__device__ __forceinline__ float sinb(float x){
    float r = x * 0.15915494309189535f;   // x / (2*pi)
    r -= floorf(r);
#if __has_builtin(__builtin_amdgcn_sinf)
    return __builtin_amdgcn_sinf(r);
#else
    return sinf(r * 6.283185307179586f);
#endif
}
__device__ __forceinline__ float cosb(float x){
    float r = x * 0.15915494309189535f;
    r -= floorf(r);
#if __has_builtin(__builtin_amdgcn_cosf)
    return __builtin_amdgcn_cosf(r);
#else
    return cosf(r * 6.283185307179586f);
#endif
}

__device__ __forceinline__ float fdot2f(half2v a, half2v b, float c){
#if __has_builtin(__builtin_amdgcn_fdot2)
    return __builtin_amdgcn_fdot2(a, b, c, false);
#else
    return fmaf((float)a[1], (float)b[1], fmaf((float)a[0], (float)b[0], c));
#endif
}

// Stage one 136x136 fp32 weight matrix (row-major [out_col][k]) into fp16 LDS [137][WP].
// Row 136 stays zero (padding row for the 9th column tile of lanes tx>=8).
__device__ __forceinline__ void stage_w(const float* __restrict__ gw,
                                        _Float16 (*wb)[WP], int t)
{
    const float4* g4 = (const float4*)gw;   // 18496 floats = 4624 float4
    #pragma unroll 1
    for (int i = t; i < (DIM*DIM)/4; i += BLOCK){
        float4 f = g4[i];
        int r  = i / 34;              // 136/4 = 34 vec4 per row
        int c4 = (i - r*34) * 4;
        half4v h;
        h[0] = (_Float16)f.x; h[1] = (_Float16)f.y;
        h[2] = (_Float16)f.z; h[3] = (_Float16)f.w;
        *(half4v*)&wb[r][c4] = h;
    }
}

// Batched matvec: out[64][136(+pad)] = src[64][136] * W^T, thread tile = 4 pts x 9 cols.
__device__ __forceinline__ void gemm136(const _Float16 (*src)[DIM],
                                        const _Float16 (*wb)[WP],
                                        int tx, int p0, float acc[4][9])
{
    #pragma unroll
    for (int pi=0; pi<4; ++pi)
        #pragma unroll
        for (int ci=0; ci<9; ++ci) acc[pi][ci] = 0.0f;

    const _Float16* wrow[9];
    #pragma unroll
    for (int ci=0; ci<9; ++ci){
        int c = tx + 16*ci;
        if (c > 136) c = 136;         // clamp padding cols to the zero row
        wrow[ci] = &wb[c][0];
    }
    #pragma unroll 1
    for (int ks = 0; ks < 17; ++ks){  // K = 136 = 17 * 8
        H8 xv[4];
        #pragma unroll
        for (int pi=0; pi<4; ++pi)
            xv[pi].v = *(const half8v*)&src[p0+pi][ks*8];
        H8 wv[9];
        #pragma unroll
        for (int ci=0; ci<9; ++ci)
            wv[ci].v = *(const half8v*)&wrow[ci][ks*8];
        #pragma unroll
        for (int pi=0; pi<4; ++pi)
            #pragma unroll
            for (int ci=0; ci<9; ++ci)
                #pragma unroll
                for (int j=0; j<4; ++j)
                    acc[pi][ci] = fdot2f(xv[pi].p[j], wv[ci].p[j], acc[pi][ci]);
    }
}

// Hash-grid trilinear features for one level: 4 lanes per point, 2 corners per lane.
__device__ __forceinline__ void grid_phase(const float* __restrict__ tables,
                                           int level, int res, int t,
                                           const float (*pin)[3], float (*vfeat)[8])
{
    const int p = t >> 2, q = t & 3;
    const float resf = (float)res;
    float fr[3]; int ip[3];
    #pragma unroll
    for (int d=0; d<3; ++d){
        float xi  = (pin[p][d] + 1.0f) * 0.5f;   // == (x+BOUND)/(2*BOUND), bit-exact
        float pos = xi * resf;
        float fl  = floorf(pos);
        fr[d] = pos - fl;
        ip[d] = (int)fl;
    }
    float acc[8];
    #pragma unroll
    for (int j=0;j<8;++j) acc[j]=0.0f;
    #pragma unroll
    for (int k=0; k<2; ++k){
        int cc = 2*q + k;
        int dx = (cc>>2)&1, dy = (cc>>1)&1, dz = cc&1;
        unsigned cx = (unsigned)(ip[0]+dx);
        unsigned cy = (unsigned)(ip[1]+dy);
        unsigned cz = (unsigned)(ip[2]+dz);
        unsigned h  = cx ^ (cy*2654435761u) ^ (cz*805459861u);
        unsigned idx = h & TMASK;
        const float* fp = tables + (size_t)level*LVLSTRIDE + (size_t)idx*8;
        float wx = dx ? fr[0] : 1.0f-fr[0];
        float wy = dy ? fr[1] : 1.0f-fr[1];
        float wz = dz ? fr[2] : 1.0f-fr[2];
        float w  = wx*wy*wz;
        float4 a = *(const float4*)fp;
        float4 b = *(const float4*)(fp+4);
        acc[0]=fmaf(w,a.x,acc[0]); acc[1]=fmaf(w,a.y,acc[1]);
        acc[2]=fmaf(w,a.z,acc[2]); acc[3]=fmaf(w,a.w,acc[3]);
        acc[4]=fmaf(w,b.x,acc[4]); acc[5]=fmaf(w,b.y,acc[5]);
        acc[6]=fmaf(w,b.z,acc[6]); acc[7]=fmaf(w,b.w,acc[7]);
    }
    #pragma unroll
    for (int j=0; j<8; ++j){
        float v = acc[j];
        v += __shfl_xor(v, 1);
        v += __shfl_xor(v, 2);
        if (q == 0) vfeat[p][j] = v;
    }
}

__global__ __launch_bounds__(BLOCK, 2)
void ffb_fused(const float* __restrict__ input, const float* __restrict__ tables,
               const float* __restrict__ W0,    const float* __restrict__ b0,
               const float* __restrict__ ffW,   const float* __restrict__ ffb,
               const float* __restrict__ oW,    const float* __restrict__ ob,
               float* __restrict__ out, int npts, FfbConsts cst)
{
    __shared__ _Float16 xbuf[BPTS][DIM];     // current x (fp16), 17408 B
    __shared__ _Float16 embbuf[BPTS][DIM];   // emb tile, 17408 B
    __shared__ _Float16 wbuf[137][WP];       // staged weights + zero row, 41648 B
    __shared__ float    vfeat[BPTS][8];      // grid features (fp32 — feeds 2^19-scaled sin)
    __shared__ float    pin[BPTS][3];        // raw input points
    __shared__ float    sfreq[8];            // posenc freqs (dynamic index -> LDS)

    const int t  = threadIdx.x;
    const int tx = t & 15;
    const int ty = t >> 4;
    const int p0 = ty * 4;
    const int base = blockIdx.x * BPTS;
    const float SW0  = (float)(M_PI * 64.0);   // 64*pi, f32-rounded like the reference
    const float SW0H = (float)(M_PI * 128.0);

    if (t < 8) sfreq[t] = cst.freqs[t];
    for (int i = t; i < WP; i += BLOCK) wbuf[136][i] = (_Float16)0.0f;
    for (int i = t; i < BPTS*3; i += BLOCK){
        int gi = base*3 + i;
        pin[i/3][i%3] = (gi < npts*3) ? input[gi] : 0.0f;
    }
    __syncthreads();

    // ---- layer 0: x = sin(w0 * (input @ W0^T + b0)), K = 3 ----
    #pragma unroll 1
    for (int pi=0; pi<4; ++pi){
        const int p = p0 + pi;
        float i0 = pin[p][0], i1 = pin[p][1], i2 = pin[p][2];
        #pragma unroll
        for (int ci=0; ci<9; ++ci){
            int c = tx + 16*ci;
            if (c < DIM){
                float pre = W0[c*3+0]*i0 + W0[c*3+1]*i1 + W0[c*3+2]*i2 + b0[c];
                xbuf[p][c] = (_Float16)sinb(SW0 * pre);
            }
        }
    }

    float xout[4][9];
    #pragma unroll
    for (int pi=0; pi<4; ++pi)
        #pragma unroll
        for (int ci=0; ci<9; ++ci) xout[pi][ci] = 0.0f;

    #pragma unroll 1
    for (int l = 1; l <= 7; ++l){
        // stage ff_W[l-1] (wbuf free: prior out-GEMM reads finished at loop-end barrier)
        stage_w(ffW + (size_t)(l-1)*DIM*DIM, wbuf, t);
        __syncthreads();                              // (B) wbuf + xbuf ready
        float acc[4][9];
        gemm136(xbuf, wbuf, tx, p0, acc);
        __syncthreads();                              // (C) all xbuf/wbuf reads done
        // ff epilogue: x <- sin(w0*(acc+b)), in-place (barrier-separated)
        #pragma unroll
        for (int pi=0; pi<4; ++pi){
            #pragma unroll
            for (int ci=0; ci<9; ++ci){
                int c = tx + 16*ci;
                if (c < DIM){
                    float pre = acc[pi][ci] + ffb[(size_t)(l-1)*DIM + c];
                    xbuf[p0+pi][c] = (_Float16)sinb(SW0 * pre);
                }
            }
        }
        // grid features for level l-1 (only level l-1 is needed this layer; level 7 never used)
        grid_phase(tables, l-1, cst.res[l-1], t, pin, vfeat);
        // stage out_W[l-1] (wbuf reads done at (C))
        stage_w(oW + (size_t)(l-1)*DIM*DIM, wbuf, t);
        __syncthreads();                              // (D) xbuf(new), vfeat, wbuf(out) ready
        // emb = posenc(v) + x : cols [0,8)=v, [8,72)=sin(v*f), [72,136)=cos(v*f)
        #pragma unroll 1
        for (int i = t; i < BPTS*DIM; i += BLOCK){
            int p = i / DIM;
            int c = i - p*DIM;
            float xv = (float)xbuf[p][c];
            float val;
            if (c < 8){
                val = vfeat[p][c];
            } else if (c < 72){
                int fi = (c-8) >> 3, qi = (c-8) & 7;
                val = sinb(vfeat[p][fi] * sfreq[qi]);
            } else {
                int fi = (c-72) >> 3, qi = (c-72) & 7;
                val = cosb(vfeat[p][fi] * sfreq[qi]);
            }
            embbuf[p][c] = (_Float16)(val + xv);
        }
        __syncthreads();                              // (E) embbuf ready
        gemm136(embbuf, wbuf, tx, p0, acc);
        #pragma unroll
        for (int pi=0; pi<4; ++pi){
            #pragma unroll
            for (int ci=0; ci<9; ++ci){
                int c = tx + 16*ci;
                if (c < DIM){
                    float pre = acc[pi][ci] + ob[(size_t)(l-1)*DIM + c];
                    xout[pi][ci] += sinb(SW0H * pre);
                }
            }
        }
        __syncthreads();                              // (F) embbuf/wbuf reads done before restage
    }

    // ---- final write: out[n] = [xin(3), x_out/8 (136)] ----
    #pragma unroll 1
    for (int pi=0; pi<4; ++pi){
        int n = base + p0 + pi;
        if (n < npts){
            size_t ro = (size_t)n * 139;
            if (tx < 3) out[ro + tx] = (pin[p0+pi][tx] + 1.0f) * 0.5f;
            #pragma unroll
            for (int ci=0; ci<9; ++ci){
                int c = tx + 16*ci;
                if (c < DIM) out[ro + 3 + c] = xout[pi][ci] * 0.125f;
            }
        }
    }
}

extern "C" void kernel_launch(void* const* d_in, const int* in_sizes, int n_in,
                              void* d_out, int out_size, void* d_ws, size_t ws_size,
                              hipStream_t stream)
{
    const float* input  = (const float*)d_in[0];
    const float* tables = (const float*)d_in[1];
    const float* W0     = (const float*)d_in[2];
    const float* b0     = (const float*)d_in[3];
    const float* ffW    = (const float*)d_in[4];
    const float* ffb    = (const float*)d_in[5];
    const float* oW     = (const float*)d_in[6];
    const float* ob     = (const float*)d_in[7];
    float* out = (float*)d_out;
    const int npts = in_sizes[0] / 3;

    // Replicate numpy's exact double-precision sequences so floor()/casts match bit-for-bit.
    FfbConsts cst;
    {
        double b = exp((log(2048.0) - log(16.0)) / 7.0);
        for (int l = 0; l < 7; ++l)
            cst.res[l] = (int)floor(16.0 * pow(b, (double)l));
        double step = 19.0 / 7.0;                    // np.linspace step
        for (int k = 0; k < 8; ++k){
            double e = (k == 7) ? 19.0 : step * (double)k;  // linspace forces endpoint
            cst.freqs[k] = (float)pow(2.0, e);
        }
    }
    int nblk = (npts + BPTS - 1) / BPTS;
    ffb_fused<<<nblk, BLOCK, 0, stream>>>(input, tables, W0, b0, ffW, ffb, oW, ob,
                                          out, npts, cst);
}

// Round 2
// 640.777 us; speedup vs baseline: 2.0986x; 2.0986x over previous
//
#include <hip/hip_runtime.h>
#include <math.h>

#ifndef M_PI
#define M_PI 3.14159265358979323846
#endif

// ---------------- architecture constants ----------------
#define BLOCK 256
#define BPTS  64            // points per block
#define DIM   136           // hidden width = 8*(1+2*8)
#define WMAT  (DIM*DIM)     // 18496 elements per weight matrix
#define NV16  (WMAT/8)      // 2312 16-byte chunks (8 halves) per fp16 matrix
#define TMASK 524287u       // T-1, T = 2^19
#define LVLSTRIDE 4194304   // T*F floats per level
#define OUTW  139           // 3 + 136 output floats per point

typedef _Float16 half8v __attribute__((ext_vector_type(8)));
typedef _Float16 half4v __attribute__((ext_vector_type(4)));
typedef float    f32x4  __attribute__((ext_vector_type(4)));

struct FfbConsts { float freqs[8]; int res[7]; };

// sin/cos via revolution-space reduction + HW v_sin/v_cos.
__device__ __forceinline__ float sinb(float x){
    float r = x * 0.15915494309189535f;
    r -= floorf(r);
#if __has_builtin(__builtin_amdgcn_sinf)
    return __builtin_amdgcn_sinf(r);
#else
    return sinf(r * 6.283185307179586f);
#endif
}
__device__ __forceinline__ float cosb(float x){
    float r = x * 0.15915494309189535f;
    r -= floorf(r);
#if __has_builtin(__builtin_amdgcn_cosf)
    return __builtin_amdgcn_cosf(r);
#else
    return cosf(r * 6.283185307179586f);
#endif
}

// ---- async global->LDS, 16B per lane (wave-uniform LDS base + lane*16) ----
__device__ __forceinline__ void gload_lds16(const void* g, void* l){
    __builtin_amdgcn_global_load_lds(
        (const __attribute__((address_space(1))) void*)g,
        (__attribute__((address_space(3))) void*)l, 16, 0, 0);
}

// Stage one fp16 weight matrix (pre-converted, row-major [outcol][k]) into LDS.
__device__ __forceinline__ void stage_async(const _Float16* __restrict__ g,
                                            _Float16* lds, int t){
    const int lane = t & 63;
    #pragma unroll 1
    for (int i = t; i < NV16; i += BLOCK){
        gload_lds16(g + (size_t)i*8, (char*)lds + (size_t)(i - lane)*16);
    }
}

// Fallback: stage from fp32 weights with in-kernel convert (used if ws too small).
__device__ __forceinline__ void stage_f32(const float* __restrict__ g,
                                          _Float16* lds, int t){
    const float4* g4 = (const float4*)g;
    #pragma unroll 1
    for (int i = t; i < WMAT/4; i += BLOCK){
        float4 f = g4[i];
        half4v h; h[0]=(_Float16)f.x; h[1]=(_Float16)f.y; h[2]=(_Float16)f.z; h[3]=(_Float16)f.w;
        *(half4v*)&lds[(size_t)i*4] = h;
    }
}

// ---- hash-grid: issue loads early (latency hides under stage drain) ----
__device__ __forceinline__ void grid_issue(const float* __restrict__ tables,
                                           int level, int res, int t,
                                           const float (*pin)[3],
                                           float w[2], float4 fa[2], float4 fb[2]){
    const int p = t >> 2, q = t & 3;
    const float resf = (float)res;
    float fr[3]; int ip[3];
    #pragma unroll
    for (int d=0; d<3; ++d){
        float xi  = (pin[p][d] + 1.0f) * 0.5f;
        float pos = xi * resf;
        float fl  = floorf(pos);
        fr[d] = pos - fl;
        ip[d] = (int)fl;
    }
    #pragma unroll
    for (int k=0; k<2; ++k){
        int cc = 2*q + k;
        int dx = (cc>>2)&1, dy = (cc>>1)&1, dz = cc&1;
        unsigned h = (unsigned)(ip[0]+dx)
                   ^ ((unsigned)(ip[1]+dy)*2654435761u)
                   ^ ((unsigned)(ip[2]+dz)*805459861u);
        unsigned idx = h & TMASK;
        const float* fp = tables + (size_t)level*LVLSTRIDE + (size_t)idx*8;
        fa[k] = *(const float4*)fp;
        fb[k] = *(const float4*)(fp+4);
        float wx = dx ? fr[0] : 1.0f-fr[0];
        float wy = dy ? fr[1] : 1.0f-fr[1];
        float wz = dz ? fr[2] : 1.0f-fr[2];
        w[k] = wx*wy*wz;
    }
}
__device__ __forceinline__ void grid_finish(int t, const float w[2],
                                            const float4 fa[2], const float4 fb[2],
                                            float* vfeat){
    const int p = t >> 2, q = t & 3;
    float acc[8];
    #pragma unroll
    for (int j=0;j<8;++j) acc[j]=0.0f;
    #pragma unroll
    for (int k=0;k<2;++k){
        acc[0]=fmaf(w[k],fa[k].x,acc[0]); acc[1]=fmaf(w[k],fa[k].y,acc[1]);
        acc[2]=fmaf(w[k],fa[k].z,acc[2]); acc[3]=fmaf(w[k],fa[k].w,acc[3]);
        acc[4]=fmaf(w[k],fb[k].x,acc[4]); acc[5]=fmaf(w[k],fb[k].y,acc[5]);
        acc[6]=fmaf(w[k],fb[k].z,acc[6]); acc[7]=fmaf(w[k],fb[k].w,acc[7]);
    }
    #pragma unroll
    for (int j=0;j<8;++j){
        float v = acc[j];
        v += __shfl_xor(v, 1);
        v += __shfl_xor(v, 2);
        if (q == 0) vfeat[p*8+j] = v;
    }
}

// ---- MFMA GEMM: C[64x136] = src[64x136] * W^T, per-wave 2 M-tiles x nt N-tiles ----
// A-frag (16x16x32): lane l holds A[l&15][(l>>4)*8 + j]; B-frag: B[k][n]=W[n][k],
// lane l holds W[l&15 + 16*ntile][(l>>4)*8 + j]. C: col=l&15, row=(l>>4)*4+r.
__device__ __forceinline__ void mfma_gemm(const _Float16* __restrict__ src,
                                          const _Float16* __restrict__ wb,
                                          int wm, int n0, int nt, int rr, int kg,
                                          f32x4 acc[2][5]){
    #pragma unroll
    for (int mi=0; mi<2; ++mi)
        #pragma unroll
        for (int ni=0; ni<5; ++ni)
            acc[mi][ni] = (f32x4){0.f,0.f,0.f,0.f};

    const _Float16* arow0 = src + (size_t)(wm*32 + rr) * DIM;
    const _Float16* arow1 = arow0 + 16*DIM;
    #pragma unroll
    for (int ks = 0; ks < 5; ++ks){
        const bool vld = (ks < 4) || (kg == 0);
        const int koff = (ks < 4) ? (ks*32 + kg*8) : 128;   // masked K-tail (136=4*32+8)
        half8v a0 = {}, a1 = {};
        half8v b[5] = {};
        if (vld){
            a0 = *(const half8v*)(arow0 + koff);
            a1 = *(const half8v*)(arow1 + koff);
            #pragma unroll
            for (int ni=0; ni<5; ++ni)
                if (ni < nt)
                    b[ni] = *(const half8v*)(wb + (size_t)((n0+ni)*16 + rr)*DIM + koff);
        }
        #pragma unroll
        for (int ni=0; ni<5; ++ni)
            if (ni < nt){
                acc[0][ni] = __builtin_amdgcn_mfma_f32_16x16x32_f16(a0, b[ni], acc[0][ni], 0,0,0);
                acc[1][ni] = __builtin_amdgcn_mfma_f32_16x16x32_f16(a1, b[ni], acc[1][ni], 0,0,0);
            }
    }
}

// ---- pre-convert all 14 weight matrices f32 -> fp16 into workspace ----
__global__ void convert_weights(const float* __restrict__ ffW,
                                const float* __restrict__ oW,
                                _Float16* __restrict__ ws){
    int i = blockIdx.x*blockDim.x + threadIdx.x;     // float4 index
    const int PER = WMAT/4;                           // 4624
    if (i < 14*PER){
        int mi = i / PER;
        int r  = i - mi*PER;
        const float* src = (mi < 7) ? (ffW + (size_t)mi*WMAT)
                                    : (oW  + (size_t)(mi-7)*WMAT);
        float4 f = *(const float4*)(src + (size_t)r*4);
        half4v h; h[0]=(_Float16)f.x; h[1]=(_Float16)f.y; h[2]=(_Float16)f.z; h[3]=(_Float16)f.w;
        *(half4v*)(ws + (size_t)i*4) = h;
    }
}

__global__ __launch_bounds__(BLOCK, 2)
void ffb_fused(const float* __restrict__ input, const float* __restrict__ tables,
               const float* __restrict__ W0,    const float* __restrict__ b0,
               const float* __restrict__ ffW,   const float* __restrict__ ffb,
               const float* __restrict__ oW,    const float* __restrict__ ob,
               const _Float16* __restrict__ w16, int use_ws,
               float* __restrict__ out, int npts, FfbConsts cst)
{
    __shared__ __align__(16) _Float16 wbuf[WMAT + 8*DIM];      // 39168 B ([144][136], rows 136-143 zero)
    __shared__ __align__(16) char     smem[BPTS*DIM*2*2 + BPTS*8*4]; // 36864 B, re-used regions
    __shared__ float pin[BPTS][3];
    __shared__ float sfreq[8];

    _Float16* xbuf   = (_Float16*)smem;                  // [64][136] fp16
    _Float16* embbuf = xbuf + BPTS*DIM;                  // [64][136] fp16
    float*    vfeat  = (float*)(smem + BPTS*DIM*4);      // [64][8]  f32
    float*    obuf   = (float*)smem;                     // [64][139] f32 (final phase only)

    const int t    = threadIdx.x;
    const int lane = t & 63;
    const int rr   = lane & 15;
    const int kg   = lane >> 4;
    const int wid  = t >> 6;
    const int wm   = wid >> 1;          // M-tile pair: rows [wm*32, wm*32+32)
    const int wn   = wid & 1;           // N slice
    const int n0   = wn ? 4 : 0;
    const int nt   = wn ? 5 : 4;
    const int base = blockIdx.x * BPTS;
    const float SW0  = (float)(M_PI * 64.0);
    const float SW0H = (float)(M_PI * 128.0);

    if (t < 8) sfreq[t] = cst.freqs[t];
    for (int i = t; i < 8*DIM; i += BLOCK) wbuf[WMAT + i] = (_Float16)0.0f;  // zero pad rows
    for (int i = t; i < BPTS*3; i += BLOCK){
        int gi = base*3 + i;
        pin[i/3][i%3] = (gi < npts*3) ? input[gi] : 0.0f;
    }
    __syncthreads();

    // ---- layer 0: x = sin(w0 * (input @ W0^T + b0)), K = 3 (VALU, tiny) ----
    #pragma unroll 1
    for (int i = t; i < BPTS*DIM; i += BLOCK){
        int p = i / DIM, c = i - p*DIM;
        float pre = W0[c*3+0]*pin[p][0] + W0[c*3+1]*pin[p][1] + W0[c*3+2]*pin[p][2] + b0[c];
        xbuf[i] = (_Float16)sinb(SW0 * pre);
    }

    float xout[2][5][4];
    #pragma unroll
    for (int mi=0; mi<2; ++mi)
        #pragma unroll
        for (int ni=0; ni<5; ++ni)
            #pragma unroll
            for (int r=0; r<4; ++r) xout[mi][ni][r] = 0.0f;

    #pragma unroll 1
    for (int l = 1; l <= 7; ++l){
        // stage ff_W[l-1] (async; wbuf reads finished at prev loop-end barrier)
        if (use_ws) stage_async(w16 + (size_t)(l-1)*WMAT, wbuf, t);
        else        stage_f32  (ffW + (size_t)(l-1)*WMAT, wbuf, t);
        // issue grid gathers for level l-1 (consumed after ff GEMM)
        float gw[2]; float4 gfa[2], gfb[2];
        grid_issue(tables, l-1, cst.res[l-1], t, pin, gw, gfa, gfb);
        __syncthreads();                               // (C) wbuf staged, xbuf ready

        f32x4 acc[2][5];
        mfma_gemm(xbuf, wbuf, wm, n0, nt, rr, kg, acc);
        __syncthreads();                               // (E) xbuf/wbuf reads done

        // stage out_W[l-1] (async, overlaps epilogue below)
        if (use_ws) stage_async(w16 + (size_t)(7 + l-1)*WMAT, wbuf, t);
        else        stage_f32  (oW  + (size_t)(l-1)*WMAT, wbuf, t);

        grid_finish(t, gw, gfa, gfb, vfeat);           // vfeat <- trilinear features

        // ff epilogue: x <- sin(w0*(acc+b)) in-place
        {
            const float* bp = ffb + (size_t)(l-1)*DIM;
            #pragma unroll
            for (int ni=0; ni<5; ++ni)
                if (ni < nt){
                    int c = (n0+ni)*16 + rr;
                    float bias = (c < DIM) ? bp[c] : 0.0f;
                    #pragma unroll
                    for (int mi=0; mi<2; ++mi)
                        #pragma unroll
                        for (int r=0; r<4; ++r){
                            if (c < DIM){
                                int p = (wm*2+mi)*16 + kg*4 + r;
                                float pre = acc[mi][ni][r] + bias;
                                xbuf[p*DIM + c] = (_Float16)sinb(SW0 * pre);
                            }
                        }
                }
        }
        __syncthreads();                               // (H) xbuf new, wbuf(out) staged, vfeat ready

        // emb = posenc(v) + x
        #pragma unroll 1
        for (int i = t; i < BPTS*DIM; i += BLOCK){
            int p = i / DIM, c = i - p*DIM;
            float xv = (float)xbuf[i];
            float val;
            if (c < 8){
                val = vfeat[p*8 + c];
            } else if (c < 72){
                int fi = (c-8) >> 3, qi = (c-8) & 7;
                val = sinb(vfeat[p*8 + fi] * sfreq[qi]);
            } else {
                int fi = (c-72) >> 3, qi = (c-72) & 7;
                val = cosb(vfeat[p*8 + fi] * sfreq[qi]);
            }
            embbuf[i] = (_Float16)(val + xv);
        }
        __syncthreads();                               // (J) embbuf ready

        mfma_gemm(embbuf, wbuf, wm, n0, nt, rr, kg, acc);
        // out epilogue -> xout regs
        {
            const float* bp = ob + (size_t)(l-1)*DIM;
            #pragma unroll
            for (int ni=0; ni<5; ++ni)
                if (ni < nt){
                    int c = (n0+ni)*16 + rr;
                    float bias = (c < DIM) ? bp[c] : 0.0f;
                    #pragma unroll
                    for (int mi=0; mi<2; ++mi)
                        #pragma unroll
                        for (int r=0; r<4; ++r){
                            if (c < DIM){
                                float pre = acc[mi][ni][r] + bias;
                                xout[mi][ni][r] += sinb(SW0H * pre);
                            }
                        }
                }
        }
        __syncthreads();                               // (M) embbuf/wbuf reads done
    }

    // ---- final: assemble [xin(3), x_out/8] per point in LDS, then coalesced store ----
    if (t < BPTS){
        obuf[t*OUTW + 0] = (pin[t][0] + 1.0f) * 0.5f;
        obuf[t*OUTW + 1] = (pin[t][1] + 1.0f) * 0.5f;
        obuf[t*OUTW + 2] = (pin[t][2] + 1.0f) * 0.5f;
    }
    #pragma unroll
    for (int ni=0; ni<5; ++ni)
        if (ni < nt){
            int c = (n0+ni)*16 + rr;
            if (c < DIM){
                #pragma unroll
                for (int mi=0; mi<2; ++mi)
                    #pragma unroll
                    for (int r=0; r<4; ++r){
                        int p = (wm*2+mi)*16 + kg*4 + r;
                        obuf[p*OUTW + 3 + c] = xout[mi][ni][r] * 0.125f;
                    }
            }
        }
    __syncthreads();
    {
        const size_t gbase = (size_t)base * OUTW;
        const size_t gend  = (size_t)npts * OUTW;
        #pragma unroll 1
        for (int i = t; i < BPTS*OUTW; i += BLOCK){
            size_t g = gbase + (size_t)i;
            if (g < gend) out[g] = obuf[i];
        }
    }
}

extern "C" void kernel_launch(void* const* d_in, const int* in_sizes, int n_in,
                              void* d_out, int out_size, void* d_ws, size_t ws_size,
                              hipStream_t stream)
{
    const float* input  = (const float*)d_in[0];
    const float* tables = (const float*)d_in[1];
    const float* W0     = (const float*)d_in[2];
    const float* b0     = (const float*)d_in[3];
    const float* ffW    = (const float*)d_in[4];
    const float* ffb    = (const float*)d_in[5];
    const float* oW     = (const float*)d_in[6];
    const float* ob     = (const float*)d_in[7];
    float* out = (float*)d_out;
    const int npts = in_sizes[0] / 3;

    // Host-side constants: identical double-precision sequences to numpy.
    FfbConsts cst;
    {
        double b = exp((log(2048.0) - log(16.0)) / 7.0);
        for (int l = 0; l < 7; ++l)
            cst.res[l] = (int)floor(16.0 * pow(b, (double)l));
        double step = 19.0 / 7.0;
        for (int k = 0; k < 8; ++k){
            double e = (k == 7) ? 19.0 : step * (double)k;
            cst.freqs[k] = (float)pow(2.0, e);
        }
    }

    const size_t need = (size_t)14 * WMAT * sizeof(_Float16);   // 517,888 B
    const int use_ws = (ws_size >= need) ? 1 : 0;
    _Float16* w16 = (_Float16*)d_ws;
    if (use_ws){
        int cblk = (14*(WMAT/4) + BLOCK-1) / BLOCK;
        convert_weights<<<cblk, BLOCK, 0, stream>>>(ffW, oW, w16);
    }
    int nblk = (npts + BPTS - 1) / BPTS;
    ffb_fused<<<nblk, BLOCK, 0, stream>>>(input, tables, W0, b0, ffW, ffb, oW, ob,
                                          w16, use_ws, out, npts, cst);
}

// Round 7
// 435.498 us; speedup vs baseline: 3.0878x; 1.4714x over previous
//
#include <hip/hip_runtime.h>
#include <math.h>

#ifndef M_PI
#define M_PI 3.14159265358979323846
#endif

// ---------------- architecture constants ----------------
#define BLOCK 256
#define BPTS  64            // points per block
#define DIM   136           // hidden width = 8*(1+2*8)
#define WMAT  (DIM*DIM)     // 18496 elements per weight matrix
#define NTILE 9             // ceil(136/16) N tiles
#define KS    5             // ceil(136/32) K steps
#define FRAGB 1024          // bytes per staged MFMA B-fragment (64 lanes x 16B)
#define MATB  (NTILE*KS*FRAGB) // 46080 B per staged matrix
#define TMASK 524287u       // T-1, T = 2^19
#define LVLSTRIDE 4194304   // T*F floats per level
#define OUTW  139           // 3 + 136 output floats per point
#define I2P   0.15915494309189535f

typedef _Float16 half8v __attribute__((ext_vector_type(8)));
typedef float    f32x4  __attribute__((ext_vector_type(4)));

struct FfbConsts { float freqs[8]; int res[7]; };

__device__ __forceinline__ float fract_(float x){ return x - floorf(x); } // v_fract
__device__ __forceinline__ float sin_rev(float r){
#if __has_builtin(__builtin_amdgcn_sinf)
    return __builtin_amdgcn_sinf(r);
#else
    return sinf(r * 6.283185307179586f);
#endif
}

// ---- fallback B-fragment from fp32 weights (only if ws too small) ----
__device__ __forceinline__ half8v bfrag_f32(const float* __restrict__ mat,
                                            int ntile, int ks, int rr, int kg){
    int row = ntile*16 + rr;
    int k0  = ks*32 + kg*8;
    half8v h = {};
    if (row < DIM){
        #pragma unroll
        for (int j=0;j<8;++j){
            int k = k0+j;
            if (k < DIM) h[j] = (_Float16)mat[row*DIM+k];
        }
    }
    return h;
}

// ---- MFMA GEMM with STREAMED B (double-buffered, 1-step prefetch) ----
// C[64x(136+pad)] = src[64x136] * W^T; A from LDS, B streamed global->VGPR.
// Live B regs: 2 x 5 x 4 = 40 VGPR (vs 100 preloaded) -> fits 170-VGPR cap, no spills.
__device__ __forceinline__ void gemm_stream(const _Float16* __restrict__ src,
                                            const char* __restrict__ stg,
                                            const float* __restrict__ f32m,
                                            int use16, int n0, int nt,
                                            int lane16, int wm, int rr, int kg,
                                            f32x4 acc[2][5])
{
    #pragma unroll
    for (int mi=0; mi<2; ++mi)
        #pragma unroll
        for (int ni=0; ni<5; ++ni)
            acc[mi][ni] = (f32x4){0.f,0.f,0.f,0.f};

    const _Float16* a0p = src + (size_t)(wm*32 + rr) * DIM;
    half8v bb0[5], bb1[5];

    #pragma unroll
    for (int ni=0; ni<5; ++ni)
        if (ni < nt)
            bb0[ni] = use16
                ? *(const half8v*)(stg + (size_t)(((n0+ni)*KS + 0)*FRAGB) + lane16)
                : bfrag_f32(f32m, n0+ni, 0, rr, kg);

    #pragma unroll
    for (int ks=0; ks<KS; ++ks){
        half8v* bc = (ks & 1) ? bb1 : bb0;   // static after unroll (no scratch)
        half8v* bn = (ks & 1) ? bb0 : bb1;
        if (ks < KS-1){
            #pragma unroll
            for (int ni=0; ni<5; ++ni)
                if (ni < nt)
                    bn[ni] = use16
                        ? *(const half8v*)(stg + (size_t)(((n0+ni)*KS + ks+1)*FRAGB) + lane16)
                        : bfrag_f32(f32m, n0+ni, ks+1, rr, kg);
        }
        const bool av  = (ks < 4) || (kg == 0);   // A tail mask (136 = 4*32 + 8)
        const int koff = ks*32 + kg*8;
        half8v a0 = {}, a1 = {};
        if (av){
            a0 = *(const half8v*)(a0p + koff);
            a1 = *(const half8v*)(a0p + 16*DIM + koff);
        }
        #pragma unroll
        for (int ni=0; ni<5; ++ni)
            if (ni < nt){
                acc[0][ni] = __builtin_amdgcn_mfma_f32_16x16x32_f16(a0, bc[ni], acc[0][ni], 0,0,0);
                acc[1][ni] = __builtin_amdgcn_mfma_f32_16x16x32_f16(a1, bc[ni], acc[1][ni], 0,0,0);
            }
    }
}

// ---- hash-grid: issue loads early, finish later ----
__device__ __forceinline__ void grid_issue(const float* __restrict__ tables,
                                           int level, int res, int t,
                                           const float (*pin)[3],
                                           float w[2], float4 fa[2], float4 fb[2]){
    const int p = t >> 2, q = t & 3;
    const float resf = (float)res;
    float fr[3]; int ip[3];
    #pragma unroll
    for (int d=0; d<3; ++d){
        float xi  = (pin[p][d] + 1.0f) * 0.5f;
        float pos = xi * resf;
        float fl  = floorf(pos);
        fr[d] = pos - fl;
        ip[d] = (int)fl;
    }
    #pragma unroll
    for (int k=0; k<2; ++k){
        int cc = 2*q + k;
        int dx = (cc>>2)&1, dy = (cc>>1)&1, dz = cc&1;
        unsigned h = (unsigned)(ip[0]+dx)
                   ^ ((unsigned)(ip[1]+dy)*2654435761u)
                   ^ ((unsigned)(ip[2]+dz)*805459861u);
        unsigned idx = h & TMASK;
        const float* fp = tables + (size_t)level*LVLSTRIDE + (size_t)idx*8;
        fa[k] = *(const float4*)fp;
        fb[k] = *(const float4*)(fp+4);
        float wx = dx ? fr[0] : 1.0f-fr[0];
        float wy = dy ? fr[1] : 1.0f-fr[1];
        float wz = dz ? fr[2] : 1.0f-fr[2];
        w[k] = wx*wy*wz;
    }
}
__device__ __forceinline__ void grid_finish(int t, const float w[2],
                                            const float4 fa[2], const float4 fb[2],
                                            float (*vfeat)[8]){
    const int p = t >> 2, q = t & 3;
    float acc[8];
    #pragma unroll
    for (int j=0;j<8;++j) acc[j]=0.0f;
    #pragma unroll
    for (int k=0;k<2;++k){
        acc[0]=fmaf(w[k],fa[k].x,acc[0]); acc[1]=fmaf(w[k],fa[k].y,acc[1]);
        acc[2]=fmaf(w[k],fa[k].z,acc[2]); acc[3]=fmaf(w[k],fa[k].w,acc[3]);
        acc[4]=fmaf(w[k],fb[k].x,acc[4]); acc[5]=fmaf(w[k],fb[k].y,acc[5]);
        acc[6]=fmaf(w[k],fb[k].z,acc[6]); acc[7]=fmaf(w[k],fb[k].w,acc[7]);
    }
    #pragma unroll
    for (int j=0;j<8;++j){
        float v = acc[j];
        v += __shfl_xor(v, 1);
        v += __shfl_xor(v, 2);
        if (q == 0) vfeat[p][j] = v;
    }
}

// ---- pre-stage all 14 weight matrices as fp16 MFMA fragments (zero-padded) ----
__global__ void convert_weights(const float* __restrict__ ffW,
                                const float* __restrict__ oW,
                                _Float16* __restrict__ ws){
    int tid = blockIdx.x*blockDim.x + threadIdx.x;
    const int total = 14*NTILE*KS*64;
    if (tid >= total) return;
    int lane = tid & 63;
    int frag = (tid >> 6) % (NTILE*KS);
    int mat  = tid / ((NTILE*KS)*64);
    int nt = frag / KS, ks = frag % KS;
    int rr = lane & 15, kg = lane >> 4;
    int row = nt*16 + rr;
    int k0  = ks*32 + kg*8;
    const float* src = (mat < 7) ? ffW + (size_t)mat*WMAT : oW + (size_t)(mat-7)*WMAT;
    half8v h = {};
    if (row < DIM){
        #pragma unroll
        for (int j=0;j<8;++j){
            int k = k0 + j;
            if (k < DIM) h[j] = (_Float16)src[(size_t)row*DIM + k];
        }
    }
    *(half8v*)((char*)ws + (size_t)mat*MATB + (size_t)frag*FRAGB + lane*16) = h;
}

__global__ __launch_bounds__(BLOCK, 3)
void ffb_fused(const float* __restrict__ input, const float* __restrict__ tables,
               const float* __restrict__ W0,    const float* __restrict__ b0,
               const float* __restrict__ ffW,   const float* __restrict__ ffb,
               const float* __restrict__ oW,    const float* __restrict__ ob,
               const _Float16* __restrict__ w16, int use_ws,
               float* __restrict__ out, int npts, FfbConsts cst)
{
    __shared__ __align__(16) char smem[BPTS*OUTW*4];   // 35584 B: xbuf+embbuf / obuf union
    __shared__ __align__(16) float vfeat[BPTS][8];     // 2048 B
    __shared__ float pin[BPTS][3];                     // 768 B
    __shared__ float sfreq[8];

    _Float16* xbuf   = (_Float16*)smem;                // [64][136]
    _Float16* embbuf = xbuf + BPTS*DIM;                // [64][136]
    float*    obuf   = (float*)smem;                   // [64][139] (final phase)

    const int t    = threadIdx.x;
    const int lane = t & 63;
    const int rr   = lane & 15;
    const int kg   = lane >> 4;
    const int lane16 = lane * 16;
    const int wid  = t >> 6;
    const int wm   = wid >> 1;
    const int wn   = wid & 1;
    const int n0   = wn ? 4 : 0;
    const int nt   = wn ? 5 : 4;
    const int base = blockIdx.x * BPTS;
    const char* wsb = (const char*)w16;

    if (t < 8) sfreq[t] = cst.freqs[t];
    for (int i = t; i < BPTS*3; i += BLOCK){
        int gi = base*3 + i;
        pin[i/3][i%3] = (gi < npts*3) ? input[gi] : 0.0f;
    }
    __syncthreads();

    // ---- layer 0: x = sin(w0*(input@W0^T+b0)); w0/2pi = 32 exactly ----
    {
        const int p = t & 63;
        const int wu = __builtin_amdgcn_readfirstlane(t >> 6);
        float i0 = pin[p][0], i1 = pin[p][1], i2 = pin[p][2];
        #pragma unroll
        for (int j = 0; j < 34; ++j){
            int c = wu*34 + j;                       // wave-uniform -> scalar W0 loads
            float pre = W0[c*3]*i0 + W0[c*3+1]*i1 + W0[c*3+2]*i2 + b0[c];
            xbuf[p*DIM + c] = (_Float16)sin_rev(fract_(pre * 32.0f));
        }
    }
    __syncthreads();                                  // xbuf(layer0) ready

    float xout[2][5][4];
    #pragma unroll
    for (int mi=0; mi<2; ++mi)
        #pragma unroll
        for (int ni=0; ni<5; ++ni)
            #pragma unroll
            for (int r=0; r<4; ++r) xout[mi][ni][r] = 0.0f;

    #pragma unroll 1
    for (int l = 1; l <= 7; ++l){
        // grid gathers for level l-1: issue early, consume after GEMM1
        float gw[2]; float4 gfa[2], gfb[2];
        grid_issue(tables, l-1, cst.res[l-1], t, pin, gw, gfa, gfb);

        f32x4 acc[2][5];
        gemm_stream(xbuf, wsb + (size_t)(l-1)*MATB, ffW + (size_t)(l-1)*WMAT,
                    use_ws, n0, nt, lane16, wm, rr, kg, acc);
        __syncthreads();                              // (C) xbuf reads done

        grid_finish(t, gw, gfa, gfb, vfeat);

        // ff epilogue: x <- sin(w0*(acc+b)) in-place; w0/2pi = 32
        {
            const float* bp = ffb + (size_t)(l-1)*DIM;
            #pragma unroll
            for (int ni=0; ni<5; ++ni)
                if (ni < nt){
                    int c = (n0+ni)*16 + rr;
                    if (c < DIM){
                        float bias = bp[c];
                        #pragma unroll
                        for (int mi=0; mi<2; ++mi)
                            #pragma unroll
                            for (int r=0; r<4; ++r){
                                int p = (wm*2+mi)*16 + kg*4 + r;
                                xbuf[p*DIM + c] =
                                    (_Float16)sin_rev(fract_((acc[mi][ni][r] + bias) * 32.0f));
                            }
                    }
                }
        }
        __syncthreads();                              // (D) xbuf new + vfeat ready

        // emb = posenc(v) + x : lane q of point p owns freqs {q, q+4}
        {
            const int p = t >> 2, q = t & 3;
            float vf[8];
            *(f32x4*)&vf[0] = *(const f32x4*)&vfeat[p][0];
            *(f32x4*)&vf[4] = *(const f32x4*)&vfeat[p][4];
            const float fA = sfreq[q]   * I2P;
            const float fB = sfreq[q+4] * I2P;
            _Float16* xb = xbuf   + p*DIM;
            _Float16* eb = embbuf + p*DIM;
            if (q == 0){
                #pragma unroll
                for (int c=0;c<8;++c) eb[c] = (_Float16)(vf[c] + (float)xb[c]);
            }
            #pragma unroll
            for (int fi=0; fi<8; ++fi){
                int cs = 8  + 8*fi + q;
                int cc = 72 + 8*fi + q;
                float rA = fract_(vf[fi]*fA);
                eb[cs]   = (_Float16)(sin_rev(rA) + (float)xb[cs]);
                eb[cc]   = (_Float16)(sin_rev(fract_(rA + 0.25f)) + (float)xb[cc]);
                float rB = fract_(vf[fi]*fB);
                eb[cs+4] = (_Float16)(sin_rev(rB) + (float)xb[cs+4]);
                eb[cc+4] = (_Float16)(sin_rev(fract_(rB + 0.25f)) + (float)xb[cc+4]);
            }
        }
        __syncthreads();                              // (E) embbuf ready

        gemm_stream(embbuf, wsb + (size_t)(7 + l-1)*MATB, oW + (size_t)(l-1)*WMAT,
                    use_ws, n0, nt, lane16, wm, rr, kg, acc);
        // out epilogue -> xout regs; 2*w0/2pi = 64
        {
            const float* bp = ob + (size_t)(l-1)*DIM;
            #pragma unroll
            for (int ni=0; ni<5; ++ni)
                if (ni < nt){
                    int c = (n0+ni)*16 + rr;
                    if (c < DIM){
                        float bias = bp[c];
                        #pragma unroll
                        for (int mi=0; mi<2; ++mi)
                            #pragma unroll
                            for (int r=0; r<4; ++r)
                                xout[mi][ni][r] +=
                                    sin_rev(fract_((acc[mi][ni][r] + bias) * 64.0f));
                    }
                }
        }
        // next iteration's GEMM1 reads xbuf (unchanged); first shared WRITE of next
        // iteration is behind (C)+(D) -> no extra barrier needed here (audited).
    }
    __syncthreads();                                  // all smem reads done -> obuf reuse

    // ---- final: assemble [xin(3), x_out/8] in LDS, then coalesced store ----
    if (t < BPTS){
        obuf[t*OUTW + 0] = (pin[t][0] + 1.0f) * 0.5f;
        obuf[t*OUTW + 1] = (pin[t][1] + 1.0f) * 0.5f;
        obuf[t*OUTW + 2] = (pin[t][2] + 1.0f) * 0.5f;
    }
    #pragma unroll
    for (int ni=0; ni<5; ++ni)
        if (ni < nt){
            int c = (n0+ni)*16 + rr;
            if (c < DIM){
                #pragma unroll
                for (int mi=0; mi<2; ++mi)
                    #pragma unroll
                    for (int r=0; r<4; ++r){
                        int p = (wm*2+mi)*16 + kg*4 + r;
                        obuf[p*OUTW + 3 + c] = xout[mi][ni][r] * 0.125f;
                    }
            }
        }
    __syncthreads();
    {
        const size_t gbase = (size_t)base * OUTW;
        const size_t gend  = (size_t)npts * OUTW;
        #pragma unroll 1
        for (int i = t; i < BPTS*OUTW; i += BLOCK){
            size_t g = gbase + (size_t)i;
            if (g < gend) out[g] = obuf[i];
        }
    }
}

extern "C" void kernel_launch(void* const* d_in, const int* in_sizes, int n_in,
                              void* d_out, int out_size, void* d_ws, size_t ws_size,
                              hipStream_t stream)
{
    const float* input  = (const float*)d_in[0];
    const float* tables = (const float*)d_in[1];
    const float* W0     = (const float*)d_in[2];
    const float* b0     = (const float*)d_in[3];
    const float* ffW    = (const float*)d_in[4];
    const float* ffb    = (const float*)d_in[5];
    const float* oW     = (const float*)d_in[6];
    const float* ob     = (const float*)d_in[7];
    float* out = (float*)d_out;
    const int npts = in_sizes[0] / 3;

    // Host-side constants: identical double-precision sequences to numpy.
    FfbConsts cst;
    {
        double b = exp((log(2048.0) - log(16.0)) / 7.0);
        for (int l = 0; l < 7; ++l)
            cst.res[l] = (int)floor(16.0 * pow(b, (double)l));
        double step = 19.0 / 7.0;
        for (int k = 0; k < 8; ++k){
            double e = (k == 7) ? 19.0 : step * (double)k;
            cst.freqs[k] = (float)pow(2.0, e);
        }
    }

    const size_t need = (size_t)14 * MATB;            // 645,120 B
    const int use_ws = (ws_size >= need) ? 1 : 0;
    _Float16* w16 = (_Float16*)d_ws;
    if (use_ws){
        const int total = 14*NTILE*KS*64;
        convert_weights<<<(total + BLOCK-1)/BLOCK, BLOCK, 0, stream>>>(ffW, oW, w16);
    }
    int nblk = (npts + BPTS - 1) / BPTS;
    ffb_fused<<<nblk, BLOCK, 0, stream>>>(input, tables, W0, b0, ffW, ffb, oW, ob,
                                          w16, use_ws, out, npts, cst);
}